// Round 1
// baseline (325.785 us; speedup 1.0000x reference)
//
#include <hip/hip_runtime.h>
#include <hip/hip_bf16.h>

typedef __bf16 bf16x8 __attribute__((ext_vector_type(8)));
typedef float  f32x4  __attribute__((ext_vector_type(4)));

#define MFMA16(a,b,c) __builtin_amdgcn_mfma_f32_16x16x32_bf16((a),(b),(c),0,0,0)

constexpr int Bb = 2048, Tt = 80, Ee = 100, Uu = 256;
constexpr int BM = 8;                 // batch rows per block
constexpr int NTHREADS = 512;         // 8 waves
constexpr int HS = 264;               // h row stride in elems (256 + 8 pad; word stride 132 == 4 mod 32)
constexpr int XS = 136;               // x row stride (128 + 8 pad)
constexpr int HBUF = 9 * HS;          // 8 data rows + 1 zero row
constexpr int XBUF = 9 * XS;

template<bool ISBF>
__device__ __forceinline__ float ldf(const void* p, int i) {
  if constexpr (ISBF) return (float)((const __bf16*)p)[i];
  else                return ((const float*)p)[i];
}

__device__ __forceinline__ float fast_tanh(float x) {
  float e = __expf(2.f * x);          // v_exp_f32; saturates correctly at +-inf
  return 1.f - 2.f / (e + 1.f);
}

// Detect whether float tensors are stored as bf16 (flag=1) or f32 (flag=0).
// For f32 data, every even 16-bit half is low mantissa bits -> decodes as a
// bf16 with a wild exponent ~84% of the time. Genuine Wh bf16 values
// (N(0,1/16)) always have exponent in [~100,126].
__global__ void detect_kernel(const void* wh, int* flag) {
  __shared__ int cnt;
  if (threadIdx.x == 0) cnt = 0;
  __syncthreads();
  const unsigned short* u = (const unsigned short*)wh;
  int c = 0;
  for (int i = threadIdx.x; i < 256; i += 64) {
    unsigned short h = u[2 * i];
    int ex = (h >> 7) & 0xFF;
    if (ex >= 135 || (ex >= 1 && ex <= 95)) c++;
  }
  atomicAdd(&cnt, c);
  __syncthreads();
  if (threadIdx.x == 0) *flag = (cnt < 64) ? 1 : 0;
}

template<bool ISBF>
__launch_bounds__(NTHREADS, 2)
__global__ void rnn_kernel(const int* __restrict__ tokens,
                           const void* __restrict__ emb,
                           const void* __restrict__ Wx0,
                           const void* __restrict__ Wx1,
                           const void* __restrict__ Wh,
                           const void* __restrict__ bias,
                           const void* __restrict__ h0g,
                           const void* __restrict__ Wo,
                           const void* __restrict__ bo,
                           void* __restrict__ out,
                           const int* __restrict__ flag) {
  if ((*flag != 0) != ISBF) return;   // wrong-dtype instantiation: whole block exits

  __shared__ __align__(16) __bf16 s_wx0[16 * 4 * 64 * 8];  // Wx0 B-frags, 64 KB
  __shared__ __align__(16) __bf16 s_h0[2 * HBUF];          // ping-pong h0 (bf16 A-tiles)
  __shared__ __align__(16) __bf16 s_h1[2 * HBUF];
  __shared__ __align__(16) __bf16 s_x [2 * XBUF];

  const int tid  = threadIdx.x;
  const int lane = tid & 63;
  const int wv   = tid >> 6;          // wave id 0..7 -> owns cols [32w, 32w+32)
  const int m    = lane & 15;         // A row / B col within tile
  const int kc   = lane >> 4;         // k-chunk 0..3
  const int b0   = blockIdx.x * BM;

  // ---- init: Wx0 fragment fill (K padded 100->128) ----
  for (int idx = tid; idx < 16 * 4 * 64 * 8; idx += NTHREADS) {
    int j = idx & 7, l = (idx >> 3) & 63, s = (idx >> 9) & 3, n = idx >> 11;
    int k = s * 32 + (l >> 4) * 8 + j;
    int c = n * 16 + (l & 15);
    s_wx0[idx] = (k < Ee) ? (__bf16)ldf<ISBF>(Wx0, k * Uu + c) : (__bf16)0.f;
  }
  // ---- zero rows (row 8 of each buffer; broadcast target for lanes m>=8) ----
  for (int idx = tid; idx < 2 * HS; idx += NTHREADS) {
    int p = idx / HS, c = idx % HS;
    s_h0[p * HBUF + 8 * HS + c] = (__bf16)0.f;
    s_h1[p * HBUF + 8 * HS + c] = (__bf16)0.f;
  }
  for (int idx = tid; idx < 2 * XS; idx += NTHREADS) {
    int p = idx / XS, c = idx % XS;
    s_x[p * XBUF + 8 * XS + c] = (__bf16)0.f;
  }
  // ---- initial hidden states (h0g layout [L,B,U]) ----
  for (int idx = tid; idx < BM * Uu; idx += NTHREADS) {
    int r = idx >> 8, c = idx & 255;
    s_h0[r * HS + c] = (__bf16)ldf<ISBF>(h0g, (b0 + r) * Uu + c);
    s_h1[r * HS + c] = (__bf16)ldf<ISBF>(h0g, Bb * Uu + (b0 + r) * Uu + c);
  }
  // ---- x_0 ----
  {
    int slot = tid;
    #pragma unroll
    for (int qq = 0; qq < 2; ++qq, slot += NTHREADS) {
      int r = slot >> 7, c = slot & 127;
      int tok = tokens[(b0 + r) * Tt + 0];
      float v = (c < Ee) ? ldf<ISBF>(emb, tok * Ee + c) : 0.f;
      s_x[r * XS + c] = (__bf16)v;
    }
  }

  // ---- persistent recurrent-weight B fragments in VGPRs (192 VGPRs) ----
  // B-frag layout for mfma_f32_16x16x32_bf16: lane holds B[k = s*32 + (lane>>4)*8 + j][n*16 + (lane&15)]
  bf16x8 fWh0[2][8], fWx1[2][8], fWh1[2][8];
  float bias0[2], bias1[2];
  #pragma unroll
  for (int e = 0; e < 2; ++e) {
    const int col = (wv * 2 + e) * 16 + m;
    bias0[e] = ldf<ISBF>(bias, col);
    bias1[e] = ldf<ISBF>(bias, Uu + col);
    #pragma unroll
    for (int s = 0; s < 8; ++s) {
      const int kb = s * 32 + kc * 8;
      bf16x8 t0, t1, t2;
      #pragma unroll
      for (int j = 0; j < 8; ++j) {
        t0[j] = (__bf16)ldf<ISBF>(Wh,  (kb + j) * Uu + col);
        t1[j] = (__bf16)ldf<ISBF>(Wx1, (kb + j) * Uu + col);
        t2[j] = (__bf16)ldf<ISBF>(Wh,  Uu * Uu + (kb + j) * Uu + col);
      }
      fWh0[e][s] = t0; fWx1[e][s] = t1; fWh1[e][s] = t2;
    }
  }

  // A-frag read offsets: row (lane&15), k-chunk (lane>>4); rows >=8 redirect to zero row 8
  const int offh = ((m < 8) ? m : 8) * HS + kc * 8;
  const int offx = ((m < 8) ? m : 8) * XS + kc * 8;
  // C/D write offset: row = (lane>>4)*4 + i, col = lane&15 (lanes < 32 hold rows 0..7)
  const int woff = ((lane >> 4) * 4) * HS + wv * 32 + m;
  const __bf16* wx0b = s_wx0 + lane * 8;

  __syncthreads();

  for (int t = 0; t < Tt; ++t) {
    const int p = t & 1;
    const int pn = p ^ 1;

    // ---- phase A: h0' = tanh(x_t@Wx0 + h0@Wh0 + b0) ----
    f32x4 acc0 = {0.f, 0.f, 0.f, 0.f};
    f32x4 acc1 = {0.f, 0.f, 0.f, 0.f};
    {
      const __bf16* ax = s_x + p * XBUF + offx;
      #pragma unroll
      for (int s = 0; s < 4; ++s) {
        bf16x8 a   = *(const bf16x8*)(ax + s * 32);
        bf16x8 bb0 = *(const bf16x8*)(wx0b + (wv * 2    ) * 2048 + s * 512);
        bf16x8 bb1 = *(const bf16x8*)(wx0b + (wv * 2 + 1) * 2048 + s * 512);
        acc0 = MFMA16(a, bb0, acc0);
        acc1 = MFMA16(a, bb1, acc1);
      }
      const __bf16* ah = s_h0 + p * HBUF + offh;
      #pragma unroll
      for (int s = 0; s < 8; ++s) {
        bf16x8 a = *(const bf16x8*)(ah + s * 32);
        acc0 = MFMA16(a, fWh0[0][s], acc0);
        acc1 = MFMA16(a, fWh0[1][s], acc1);
      }
    }
    // stage x_{t+1} while MFMAs drain (hides emb gather latency)
    if (t + 1 < Tt) {
      __bf16* xw = s_x + pn * XBUF;
      int slot = tid;
      #pragma unroll
      for (int qq = 0; qq < 2; ++qq, slot += NTHREADS) {
        int r = slot >> 7, c = slot & 127;
        int tok = tokens[(b0 + r) * Tt + t + 1];
        float v = (c < Ee) ? ldf<ISBF>(emb, tok * Ee + c) : 0.f;
        xw[r * XS + c] = (__bf16)v;
      }
    }
    if (lane < 32) {
      __bf16* wp = s_h0 + pn * HBUF + woff;
      #pragma unroll
      for (int i = 0; i < 4; ++i) {
        wp[i * HS]      = (__bf16)fast_tanh(acc0[i] + bias0[0]);
        wp[i * HS + 16] = (__bf16)fast_tanh(acc1[i] + bias0[1]);
      }
    }
    __syncthreads();

    // ---- phase B: h1' = tanh(h0'@Wx1 + h1@Wh1 + b1) ----
    acc0 = (f32x4){0.f, 0.f, 0.f, 0.f};
    acc1 = (f32x4){0.f, 0.f, 0.f, 0.f};
    {
      const __bf16* ahn = s_h0 + pn * HBUF + offh;
      #pragma unroll
      for (int s = 0; s < 8; ++s) {
        bf16x8 a = *(const bf16x8*)(ahn + s * 32);
        acc0 = MFMA16(a, fWx1[0][s], acc0);
        acc1 = MFMA16(a, fWx1[1][s], acc1);
      }
      const __bf16* ah1 = s_h1 + p * HBUF + offh;
      #pragma unroll
      for (int s = 0; s < 8; ++s) {
        bf16x8 a = *(const bf16x8*)(ah1 + s * 32);
        acc0 = MFMA16(a, fWh1[0][s], acc0);
        acc1 = MFMA16(a, fWh1[1][s], acc1);
      }
    }
    if (lane < 32) {
      __bf16* wp = s_h1 + pn * HBUF + woff;
      #pragma unroll
      for (int i = 0; i < 4; ++i) {
        wp[i * HS]      = (__bf16)fast_tanh(acc0[i] + bias1[0]);
        wp[i * HS + 16] = (__bf16)fast_tanh(acc1[i] + bias1[1]);
      }
    }
    __syncthreads();
  }

  // ---- epilogue: sigmoid(h1_final @ Wo + bo); t=79 wrote parity 0 ----
  if (tid < BM) {
    const int r = tid;
    float z = ldf<ISBF>(bo, 0);
    const __bf16* hrow = s_h1 + r * HS;
    #pragma unroll 8
    for (int c = 0; c < Uu; ++c)
      z += (float)hrow[c] * ldf<ISBF>(Wo, c);
    float sg = 1.f / (1.f + __expf(-z));
    if constexpr (ISBF) ((__bf16*)out)[b0 + r] = (__bf16)sg;
    else                ((float*)out)[b0 + r]  = sg;
  }
}

extern "C" void kernel_launch(void* const* d_in, const int* in_sizes, int n_in,
                              void* d_out, int out_size, void* d_ws, size_t ws_size,
                              hipStream_t stream) {
  const int*  tokens = (const int*)d_in[0];
  const void* emb = d_in[1];
  const void* Wx0 = d_in[2];
  const void* Wx1 = d_in[3];
  const void* Wh  = d_in[4];
  const void* b   = d_in[5];
  const void* h0  = d_in[6];
  const void* Wo  = d_in[7];
  const void* bo  = d_in[8];
  int* flag = (int*)d_ws;

  detect_kernel<<<1, 64, 0, stream>>>(Wh, flag);
  rnn_kernel<true ><<<dim3(Bb / BM), dim3(NTHREADS), 0, stream>>>(
      tokens, emb, Wx0, Wx1, Wh, b, h0, Wo, bo, d_out, flag);
  rnn_kernel<false><<<dim3(Bb / BM), dim3(NTHREADS), 0, stream>>>(
      tokens, emb, Wx0, Wx1, Wh, b, h0, Wo, bo, d_out, flag);
}

// Round 2
// 322.491 us; speedup vs baseline: 1.0102x; 1.0102x over previous
//
#include <hip/hip_runtime.h>
#include <hip/hip_bf16.h>

typedef __bf16 bf16x8 __attribute__((ext_vector_type(8)));
typedef float  f32x4  __attribute__((ext_vector_type(4)));

#define MFMA16(a,b,c) __builtin_amdgcn_mfma_f32_16x16x32_bf16((a),(b),(c),0,0,0)

constexpr int Bb = 2048, Tt = 80, Ee = 100, Uu = 256;
constexpr int BM = 8;                 // batch rows per rnn block
constexpr int NT = 512;               // 8 waves
constexpr int HCH = 256;              // elems per k-chunk in frag layout (32 units x 8)
constexpr int HB = 8 * HCH;           // one h buffer (K=256 -> 8 chunks)
constexpr int XB = 4 * HCH;           // one x buffer (K=128 -> 4 chunks), fallback only

template<bool ISBF>
__device__ __forceinline__ float ldf(const void* p, int i) {
  if constexpr (ISBF) return (float)((const __bf16*)p)[i];
  else                return ((const float*)p)[i];
}

__device__ __forceinline__ float fast_tanh(float x) {
  float e = __expf(2.f * x);
  return 1.f - 2.f / (e + 1.f);
}

// Detect bf16 (flag=1) vs f32 (flag=0) storage of the float tensors.
__global__ void detect_kernel(const void* wh, int* flag) {
  __shared__ int cnt;
  if (threadIdx.x == 0) cnt = 0;
  __syncthreads();
  const unsigned short* u = (const unsigned short*)wh;
  int c = 0;
  for (int i = threadIdx.x; i < 256; i += 64) {
    unsigned short h = u[2 * i];
    int ex = (h >> 7) & 0xFF;
    if (ex >= 135 || (ex >= 1 && ex <= 95)) c++;
  }
  atomicAdd(&cnt, c);
  __syncthreads();
  if (threadIdx.x == 0) *flag = (cnt < 64) ? 1 : 0;
}

// ---------------- pre-GEMM: U[m,c] = (emb[tokens[m]] @ Wx0)[c], bf16 out ----
// m = b*T + t (tokens is [B,T] row-major => token = tokens[m] directly).
// Block: 64 rows x 256 cols, 8 waves (wave wv owns cols 32*wv..+32).
template<bool ISBF>
__launch_bounds__(NT, 2)
__global__ void pregemm_kernel(const int* __restrict__ tokens,
                               const void* __restrict__ emb,
                               const void* __restrict__ Wx0,
                               __bf16* __restrict__ U,
                               const int* __restrict__ flag) {
  if ((*flag != 0) != ISBF) return;
  __shared__ __align__(16) __bf16 s_a[16 * 512];  // 16 chunks x 64 units x 8
  const int tid = threadIdx.x, lane = tid & 63, wv = tid >> 6;
  const int m = lane & 15, kc = lane >> 4;
  const int m0 = blockIdx.x * 64;

  for (int idx = tid; idx < 64 * 128; idx += NT) {
    int r = idx >> 7, c = idx & 127;
    int tok = tokens[m0 + r];
    float v = (c < Ee) ? ldf<ISBF>(emb, tok * Ee + c) : 0.f;
    int off = ((r >> 4) * 4 + (c >> 5)) * 512 + (((c >> 3) & 3) * 16 + (r & 15)) * 8 + (c & 7);
    s_a[off] = (__bf16)v;
  }
  bf16x8 fB[2][4];
  #pragma unroll
  for (int e = 0; e < 2; ++e) {
    const int col = wv * 32 + e * 16 + m;
    #pragma unroll
    for (int s = 0; s < 4; ++s) {
      bf16x8 tr;
      #pragma unroll
      for (int j = 0; j < 8; ++j) {
        int k = s * 32 + kc * 8 + j;
        tr[j] = (k < Ee) ? (__bf16)ldf<ISBF>(Wx0, k * Uu + col) : (__bf16)0.f;
      }
      fB[e][s] = tr;
    }
  }
  __syncthreads();
  const int au = (kc * 16 + m) * 8;
  #pragma unroll
  for (int g = 0; g < 4; ++g) {
    f32x4 a0 = {0.f,0.f,0.f,0.f}, a1 = {0.f,0.f,0.f,0.f};
    #pragma unroll
    for (int s = 0; s < 4; ++s) {
      bf16x8 a = *(const bf16x8*)(s_a + (g * 4 + s) * 512 + au);
      a0 = MFMA16(a, fB[0][s], a0);
      a1 = MFMA16(a, fB[1][s], a1);
    }
    const int rb = (lane >> 4) * 4;
    #pragma unroll
    for (int i = 0; i < 4; ++i) {
      size_t mr = (size_t)(m0 + g * 16 + rb + i) * Uu;
      U[mr + wv * 32 + m]      = (__bf16)a0[i];
      U[mr + wv * 32 + 16 + m] = (__bf16)a1[i];
    }
  }
}

// ---------------- persistent 2-layer RNN scan -------------------------------
// h stored in LDS in MFMA A-frag order: elem(row,k) at (k>>5)*HCH +
// (((k>>3)&3)*8 + row)*8 + (k&7). Lanes m>=8 broadcast-read row m-8 (free);
// garbage C rows 8..15 sit in lanes 32..63 and are discarded.
template<bool ISBF, bool PRE>
__launch_bounds__(NT, 2)
__global__ void rnn_kernel(const int* __restrict__ tokens,
                           const void* __restrict__ emb,
                           const void* __restrict__ Wx0,
                           const void* __restrict__ Wx1,
                           const void* __restrict__ Wh,
                           const void* __restrict__ bias,
                           const void* __restrict__ h0g,
                           const void* __restrict__ Wo,
                           const void* __restrict__ bo,
                           const __bf16* __restrict__ U,
                           void* __restrict__ out,
                           const int* __restrict__ flag) {
  if ((*flag != 0) != ISBF) return;

  __shared__ __align__(16) __bf16 s_h0[2 * HB];
  __shared__ __align__(16) __bf16 s_h1[2 * HB];
  __shared__ __align__(16) __bf16 s_x[PRE ? 16 : 2 * XB];

  const int tid = threadIdx.x, lane = tid & 63, wv = tid >> 6;
  const int m = lane & 15, kc = lane >> 4;
  const int b0 = blockIdx.x * BM;
  const int au = (kc * 8 + (m & 7)) * 8;   // A-frag read offset (broadcast for m>=8)

  // initial h frags (parity 0)
  for (int idx = tid; idx < BM * Uu; idx += NT) {
    int r = idx >> 8, c = idx & 255;
    int off = (c >> 5) * HCH + (((c >> 3) & 3) * 8 + r) * 8 + (c & 7);
    s_h0[off] = (__bf16)ldf<ISBF>(h0g, (b0 + r) * Uu + c);
    s_h1[off] = (__bf16)ldf<ISBF>(h0g, Bb * Uu + (b0 + r) * Uu + c);
  }
  if constexpr (!PRE) {
    for (int idx = tid; idx < BM * 128; idx += NT) {
      int r = idx >> 7, c = idx & 127;
      int tok = tokens[(b0 + r) * Tt];
      float v = (c < Ee) ? ldf<ISBF>(emb, tok * Ee + c) : 0.f;
      int off = (c >> 5) * HCH + (((c >> 3) & 3) * 8 + r) * 8 + (c & 7);
      s_x[off] = (__bf16)v;
    }
  }

  // persistent weight B-frags
  bf16x8 fWh0[2][8], fWx1[2][8], fWh1[2][8];
  bf16x8 fWx0[2][PRE ? 1 : 4];
  float bias0[2], bias1[2];
  #pragma unroll
  for (int e = 0; e < 2; ++e) {
    const int col = (wv * 2 + e) * 16 + m;
    bias0[e] = ldf<ISBF>(bias, col);
    bias1[e] = ldf<ISBF>(bias, Uu + col);
    #pragma unroll
    for (int s = 0; s < 8; ++s) {
      const int kb = s * 32 + kc * 8;
      bf16x8 t0, t1, t2;
      #pragma unroll
      for (int j = 0; j < 8; ++j) {
        t0[j] = (__bf16)ldf<ISBF>(Wh,  (kb + j) * Uu + col);
        t1[j] = (__bf16)ldf<ISBF>(Wx1, (kb + j) * Uu + col);
        t2[j] = (__bf16)ldf<ISBF>(Wh,  Uu * Uu + (kb + j) * Uu + col);
      }
      fWh0[e][s] = t0; fWx1[e][s] = t1; fWh1[e][s] = t2;
    }
    if constexpr (!PRE) {
      #pragma unroll
      for (int s = 0; s < 4; ++s) {
        bf16x8 t3;
        #pragma unroll
        for (int j = 0; j < 8; ++j) {
          int k = s * 32 + kc * 8 + j;
          t3[j] = (k < Ee) ? (__bf16)ldf<ISBF>(Wx0, k * Uu + col) : (__bf16)0.f;
        }
        fWx0[e][s] = t3;
      }
    }
  }

  // h-write decomposition (lanes<32 own C rows 0..7)
  const int kc2 = (lane & 15) >> 3, rb2 = (lane >> 4) * 4, j2 = lane & 7;

  float up0[4], up1[4];
  const int rbu = ((lane >> 4) & 1) * 4;
  if constexpr (PRE) {
    const __bf16* Ub = U + (size_t)(b0 + rbu) * Tt * Uu + wv * 32 + m;
    #pragma unroll
    for (int i = 0; i < 4; ++i) {
      up0[i] = (float)Ub[(size_t)i * Tt * Uu];
      up1[i] = (float)Ub[(size_t)i * Tt * Uu + 16];
    }
  }

  __syncthreads();

  for (int t = 0; t < Tt; ++t) {
    const int p = t & 1, pn = p ^ 1;

    // ---- phase A: h0' = tanh(u_t + h0@Wh0 + b0) ----
    f32x4 acc0, acc1;
    if constexpr (PRE) {
      acc0 = (f32x4){up0[0], up0[1], up0[2], up0[3]};
      acc1 = (f32x4){up1[0], up1[1], up1[2], up1[3]};
    } else {
      f32x4 x0 = {0.f,0.f,0.f,0.f}, x1 = {0.f,0.f,0.f,0.f};
      const __bf16* xb = s_x + p * XB + au;
      #pragma unroll
      for (int s = 0; s < 4; ++s) {
        bf16x8 a = *(const bf16x8*)(xb + s * HCH);
        x0 = MFMA16(a, fWx0[0][s], x0);
        x1 = MFMA16(a, fWx0[1][s], x1);
      }
      acc0 = x0; acc1 = x1;
    }
    {
      const __bf16* hb = s_h0 + p * HB + au;
      #pragma unroll
      for (int s = 0; s < 8; ++s) {
        bf16x8 a = *(const bf16x8*)(hb + s * HCH);
        acc0 = MFMA16(a, fWh0[0][s], acc0);
        acc1 = MFMA16(a, fWh0[1][s], acc1);
      }
    }
    if (lane < 32) {
      __bf16* wp = s_h0 + pn * HB + wv * HCH + j2;
      #pragma unroll
      for (int i = 0; i < 4; ++i) {
        wp[((0 + kc2) * 8 + rb2 + i) * 8] = (__bf16)fast_tanh(acc0[i] + bias0[0]);
        wp[((2 + kc2) * 8 + rb2 + i) * 8] = (__bf16)fast_tanh(acc1[i] + bias0[1]);
      }
    }
    __syncthreads();

    // prefetch u_{t+1} here: phase-B MFMA window covers the pre-barrier drain
    if constexpr (PRE) {
      int tn = (t + 1 < Tt) ? t + 1 : Tt - 1;
      const __bf16* Ub = U + (size_t)((b0 + rbu) * Tt + tn) * Uu + wv * 32 + m;
      #pragma unroll
      for (int i = 0; i < 4; ++i) {
        up0[i] = (float)Ub[(size_t)i * Tt * Uu];
        up1[i] = (float)Ub[(size_t)i * Tt * Uu + 16];
      }
    }

    // ---- phase B: h1' = tanh(h0'@Wx1 + h1@Wh1 + b1), 4 acc chains ----
    f32x4 ba0 = {0.f,0.f,0.f,0.f}, ba1 = {0.f,0.f,0.f,0.f};
    f32x4 ca0 = {0.f,0.f,0.f,0.f}, ca1 = {0.f,0.f,0.f,0.f};
    {
      const __bf16* hb = s_h0 + pn * HB + au;
      #pragma unroll
      for (int s = 0; s < 8; ++s) {
        bf16x8 a = *(const bf16x8*)(hb + s * HCH);
        ba0 = MFMA16(a, fWx1[0][s], ba0);
        ba1 = MFMA16(a, fWx1[1][s], ba1);
      }
      const __bf16* h1b = s_h1 + p * HB + au;
      #pragma unroll
      for (int s = 0; s < 8; ++s) {
        bf16x8 a = *(const bf16x8*)(h1b + s * HCH);
        ca0 = MFMA16(a, fWh1[0][s], ca0);
        ca1 = MFMA16(a, fWh1[1][s], ca1);
      }
    }
    if constexpr (!PRE) {
      if (t + 1 < Tt) {
        int slot = tid;
        #pragma unroll
        for (int q = 0; q < 2; ++q, slot += NT) {
          int r = slot >> 7, c = slot & 127;
          int tok = tokens[(b0 + r) * Tt + t + 1];
          float v = (c < Ee) ? ldf<ISBF>(emb, tok * Ee + c) : 0.f;
          int off = (c >> 5) * HCH + (((c >> 3) & 3) * 8 + r) * 8 + (c & 7);
          s_x[pn * XB + off] = (__bf16)v;
        }
      }
    }
    acc0 = ba0 + ca0; acc1 = ba1 + ca1;
    if (lane < 32) {
      __bf16* wp = s_h1 + pn * HB + wv * HCH + j2;
      #pragma unroll
      for (int i = 0; i < 4; ++i) {
        wp[((0 + kc2) * 8 + rb2 + i) * 8] = (__bf16)fast_tanh(acc0[i] + bias1[0]);
        wp[((2 + kc2) * 8 + rb2 + i) * 8] = (__bf16)fast_tanh(acc1[i] + bias1[1]);
      }
    }
    __syncthreads();
  }

  // ---- epilogue: sigmoid(h1 @ Wo + bo); final h1 at parity 0 ----
  if (tid < 256) {
    const int r = tid >> 5, q = tid & 31;
    const __bf16* hp = s_h1 + (q >> 2) * HCH + ((q & 3) * 8 + r) * 8;
    bf16x8 hv = *(const bf16x8*)hp;
    float part = 0.f;
    #pragma unroll
    for (int j = 0; j < 8; ++j) part += (float)hv[j] * ldf<ISBF>(Wo, q * 8 + j);
    #pragma unroll
    for (int o = 16; o >= 1; o >>= 1) part += __shfl_down(part, o, 32);
    if (q == 0) {
      float z = part + ldf<ISBF>(bo, 0);
      float sg = 1.f / (1.f + __expf(-z));
      if constexpr (ISBF) ((__bf16*)out)[b0 + r] = (__bf16)sg;
      else                ((float*)out)[b0 + r]  = sg;
    }
  }
}

extern "C" void kernel_launch(void* const* d_in, const int* in_sizes, int n_in,
                              void* d_out, int out_size, void* d_ws, size_t ws_size,
                              hipStream_t stream) {
  const int*  tokens = (const int*)d_in[0];
  const void* emb = d_in[1];
  const void* Wx0 = d_in[2];
  const void* Wx1 = d_in[3];
  const void* Wh  = d_in[4];
  const void* b   = d_in[5];
  const void* h0  = d_in[6];
  const void* Wo  = d_in[7];
  const void* bo  = d_in[8];

  int* flag = (int*)d_ws;
  __bf16* U = (__bf16*)((char*)d_ws + 256);
  const size_t needU = 256 + (size_t)Bb * Tt * Uu * sizeof(__bf16);  // ~84 MB
  const bool pre = (ws_size >= needU);   // ws_size constant across calls -> same work every call

  detect_kernel<<<1, 64, 0, stream>>>(Wh, flag);
  if (pre) {
    pregemm_kernel<true ><<<dim3((Bb * Tt) / 64), dim3(NT), 0, stream>>>(tokens, emb, Wx0, U, flag);
    pregemm_kernel<false><<<dim3((Bb * Tt) / 64), dim3(NT), 0, stream>>>(tokens, emb, Wx0, U, flag);
    rnn_kernel<true , true ><<<dim3(Bb / BM), dim3(NT), 0, stream>>>(
        tokens, emb, Wx0, Wx1, Wh, b, h0, Wo, bo, U, d_out, flag);
    rnn_kernel<false, true ><<<dim3(Bb / BM), dim3(NT), 0, stream>>>(
        tokens, emb, Wx0, Wx1, Wh, b, h0, Wo, bo, U, d_out, flag);
  } else {
    rnn_kernel<true , false><<<dim3(Bb / BM), dim3(NT), 0, stream>>>(
        tokens, emb, Wx0, Wx1, Wh, b, h0, Wo, bo, U, d_out, flag);
    rnn_kernel<false, false><<<dim3(Bb / BM), dim3(NT), 0, stream>>>(
        tokens, emb, Wx0, Wx1, Wh, b, h0, Wo, bo, U, d_out, flag);
  }
}